// Round 1
// baseline (3934.510 us; speedup 1.0000x reference)
//
#include <hip/hip_runtime.h>

#define Bq 8
#define Tq 2048
#define Dq 512
#define Wq 5

// ---------------------------------------------------------------------------
// Wave-wide sum (64 lanes) via shfl_xor butterfly: all lanes get the total.
// ---------------------------------------------------------------------------
__device__ __forceinline__ float wave_sum(float v) {
  v += __shfl_xor(v, 1);
  v += __shfl_xor(v, 2);
  v += __shfl_xor(v, 4);
  v += __shfl_xor(v, 8);
  v += __shfl_xor(v, 16);
  v += __shfl_xor(v, 32);
  return v;
}

__device__ __forceinline__ void load_row8(const float* __restrict__ base, int r,
                                          int lane, float dst[8]) {
  const float4* p = reinterpret_cast<const float4*>(base + (size_t)r * Dq) + lane * 2;
  float4 a = p[0];
  float4 c = p[1];
  dst[0] = a.x; dst[1] = a.y; dst[2] = a.z; dst[3] = a.w;
  dst[4] = c.x; dst[5] = c.y; dst[6] = c.z; dst[7] = c.w;
}

// ---------------------------------------------------------------------------
// One scan step. Slots S0..S4 hold window rows for j=0..4 (compile-time ring
// positions so everything stays in registers). SL = slot that receives the
// prefetched row t+3 at the end of the step. m3/m4 are validity masks for
// j=3,4 (j=0..2 are always valid since nvalid >= 3 for all t).
// Padded j contribute score EXACTLY 0 (they still get exp(0) weight in the
// softmax denominator, matching the reference), and 0 to attn/G sums.
// ---------------------------------------------------------------------------
template <int S0, int S1, int S2, int S3, int S4, int SL>
__device__ __forceinline__ void scan_step(
    int t, float m3, float m4,
    const float* __restrict__ ob, const float* __restrict__ Gb,
    const float* __restrict__ Pgb, float* __restrict__ po,
    float ow[Wq][8], float gw[Wq][8], float st[8], int lane) {
  float no[8], ng[8], pg[8], pm[8];
  int rl = t + 3;
  if (rl > Tq - 1) rl = Tq - 1;
  // Prefetch next window row + per-t precomputed rows early (state-independent).
  load_row8(ob, rl, lane, no);
  load_row8(Gb, rl, lane, ng);
  load_row8(Pgb, t, lane, pg);
  load_row8(po, t, lane, pm);  // po currently holds PRE_mlp at row t (in-place)

  // scores: s_j = state . o_row_j  (per-lane partial over 8 dims)
  float s0 = 0.f, s1 = 0.f, s2 = 0.f, s3 = 0.f, s4 = 0.f;
#pragma unroll
  for (int i = 0; i < 8; i++) {
    float sv = st[i];
    s0 = fmaf(sv, ow[S0][i], s0);
    s1 = fmaf(sv, ow[S1][i], s1);
    s2 = fmaf(sv, ow[S2][i], s2);
    s3 = fmaf(sv, ow[S3][i], s3);
    s4 = fmaf(sv, ow[S4][i], s4);
  }
  const float scale = 0.04419417382415922f;  // 1/sqrt(512)
  s0 = wave_sum(s0) * scale;
  s1 = wave_sum(s1) * scale;
  s2 = wave_sum(s2) * scale;
  s3 = wave_sum(s3) * scale * m3;  // masked scores forced to exact 0
  s4 = wave_sum(s4) * scale * m4;

  float mx = fmaxf(fmaxf(fmaxf(s0, s1), fmaxf(s2, s3)), s4);
  float e0 = __expf(s0 - mx), e1 = __expf(s1 - mx), e2 = __expf(s2 - mx);
  float e3 = __expf(s3 - mx), e4 = __expf(s4 - mx);
  float inv = __fdividef(1.0f, e0 + e1 + e2 + e3 + e4);
  // q_j: prob for vector contributions — zero for padded j (their window row is 0)
  float q0 = e0 * inv, q1 = e1 * inv, q2 = e2 * inv;
  float q3 = e3 * inv * m3, q4 = e4 * inv * m4;

  float at_[8], gs_[8];
#pragma unroll
  for (int i = 0; i < 8; i++) {
    at_[i] = q0 * ow[S0][i] + q1 * ow[S1][i] + q2 * ow[S2][i] +
             q3 * ow[S3][i] + q4 * ow[S4][i];
    gs_[i] = q0 * gw[S0][i] + q1 * gw[S1][i] + q2 * gw[S2][i] +
             q3 * gw[S3][i] + q4 * gw[S4][i];
  }

  float ot[8];
#pragma unroll
  for (int i = 0; i < 8; i++) {
    float x = pg[i] + gs_[i];
    float gate = __fdividef(1.0f, 1.0f + __expf(-x));
    ot[i] = pm[i] + at_[i] * gate;
    st[i] = ot[i];
  }
  float4* dst = reinterpret_cast<float4*>(po + (size_t)t * Dq) + lane * 2;
  dst[0] = make_float4(ot[0], ot[1], ot[2], ot[3]);
  dst[1] = make_float4(ot[4], ot[5], ot[6], ot[7]);

  // Commit prefetched row t+3 into its ring slot (old contents now dead).
#pragma unroll
  for (int i = 0; i < 8; i++) {
    ow[SL][i] = no[i];
    gw[SL][i] = ng[i];
  }
}

// ---------------------------------------------------------------------------
// Sequential scan: one block (one wave) per batch b. 8 blocks total.
// Lane l owns dims [8l, 8l+8).
// ---------------------------------------------------------------------------
__global__ __launch_bounds__(64, 1) void scan_kernel(
    const float* __restrict__ O, const float* __restrict__ Gm,
    const float* __restrict__ Pg, float* __restrict__ out) {
  int b = blockIdx.x;
  int lane = threadIdx.x;
  const float* ob = O + (size_t)b * Tq * Dq;
  const float* Gb = Gm + (size_t)b * Tq * Dq;
  const float* Pgb = Pg + (size_t)b * Tq * Dq;
  float* po = out + (size_t)b * Tq * Dq;

  float ow[Wq][8], gw[Wq][8], st[8];
#pragma unroll
  for (int s = 0; s < Wq; s++)
#pragma unroll
    for (int i = 0; i < 8; i++) {
      ow[s][i] = 0.f;
      gw[s][i] = 0.f;
    }
#pragma unroll
  for (int i = 0; i < 8; i++) st[i] = 0.f;

  // Preload rows 0,1,2 into slots 0,1,2 (slot = row % 5 from here on).
  load_row8(ob, 0, lane, ow[0]); load_row8(Gb, 0, lane, gw[0]);
  load_row8(ob, 1, lane, ow[1]); load_row8(Gb, 1, lane, gw[1]);
  load_row8(ob, 2, lane, ow[2]); load_row8(Gb, 2, lane, gw[2]);

  // t=0: rows {0,1,2} valid (nvalid=3); prefetch row 3 -> slot 3
  scan_step<0, 1, 2, 3, 4, 3>(0, 0.f, 0.f, ob, Gb, Pgb, po, ow, gw, st, lane);
  // t=1: rows {0,1,2,3} valid; prefetch row 4 -> slot 4
  scan_step<0, 1, 2, 3, 4, 4>(1, 1.f, 0.f, ob, Gb, Pgb, po, ow, gw, st, lane);

  // Main loop t=2..2046 (2045 steps = 409 * 5), phases cycle; slot(j) = (t-2+j)%5.
  for (int tb = 2; tb <= Tq - 6; tb += 5) {
    scan_step<0, 1, 2, 3, 4, 0>(tb + 0, 1.f, 1.f, ob, Gb, Pgb, po, ow, gw, st, lane);
    scan_step<1, 2, 3, 4, 0, 1>(tb + 1, 1.f, 1.f, ob, Gb, Pgb, po, ow, gw, st, lane);
    scan_step<2, 3, 4, 0, 1, 2>(tb + 2, 1.f, 1.f, ob, Gb, Pgb, po, ow, gw, st, lane);
    scan_step<3, 4, 0, 1, 2, 3>(tb + 3, 1.f, 1.f, ob, Gb, Pgb, po, ow, gw, st, lane);
    scan_step<4, 0, 1, 2, 3, 4>(tb + 4, 1.f,
                                (tb + 4 <= Tq - 3) ? 1.f : 0.f,  // t=2046 -> m4=0
                                ob, Gb, Pgb, po, ow, gw, st, lane);
  }
  // t = 2047: rows {2045,2046,2047} valid (nvalid=3)
  scan_step<0, 1, 2, 3, 4, 0>(Tq - 1, 0.f, 0.f, ob, Gb, Pgb, po, ow, gw, st, lane);
}

// ---------------------------------------------------------------------------
// Precompute GEMMs (f32, LDS-tiled 128x128x16, 8x8 microtile, 256 threads).
// mode 0: C[bt, n] over windowed A (K = 5*512), n<512 -> PRE_mlp (+b_mlp),
//         n>=512 -> PRE_gate (+b_gate).
// mode 1: G[bt, n] = O[bt,:] @ W_gate[:, 2560:].T  (K = 512, no bias).
// ---------------------------------------------------------------------------
__global__ __launch_bounds__(256) void gemm_pre(
    const float* __restrict__ O, const float* __restrict__ Wm,
    const float* __restrict__ Wg, const float* __restrict__ bm,
    const float* __restrict__ bg, float* __restrict__ Pm,
    float* __restrict__ Pg, float* __restrict__ Gm, int mode) {
  const int BM = 128, BN = 128, BK = 16;
  __shared__ float As[BK][132];  // [k][m], padded
  __shared__ float Bs[BK][132];  // [k][n], padded

  int tidx = threadIdx.x;
  int bt0 = blockIdx.x * BM;
  int b = bt0 / Tq;   // tile never crosses a batch boundary (2048 % 128 == 0)
  int t0 = bt0 % Tq;
  int n0 = blockIdx.y * BN;
  int K = mode ? Dq : Wq * Dq;

  int tx = tidx % 16;       // n-dir
  int ty = tidx / 16;       // m-dir
  int lr = tidx >> 2;       // 0..63: staging row
  int lc = (tidx & 3) * 4;  // staging col4: 0,4,8,12

  float acc[8][8];
#pragma unroll
  for (int i = 0; i < 8; i++)
#pragma unroll
    for (int j = 0; j < 8; j++) acc[i][j] = 0.f;

  for (int kb = 0; kb < K; kb += BK) {
    // ---- stage A tile (with window gather for mode 0) ----
#pragma unroll
    for (int h = 0; h < 2; h++) {
      int m = lr + h * 64;
      int t = t0 + m;
      float4 av;
      if (mode == 0) {
        int j = kb >> 9;              // window block (BK chunk never straddles)
        int kcol = (kb & 511) + lc;
        int sh = 2 - t; if (sh < 0) sh = 0;
        int r = t - 2 + j + sh;
        int hi = t + 2; if (hi > Tq - 1) hi = Tq - 1;
        int lo = t - 2; if (lo < 0) lo = 0;
        int nv = hi - lo + 1;
        if (j < nv) {
          av = *reinterpret_cast<const float4*>(O + ((size_t)b * Tq + r) * Dq + kcol);
        } else {
          av = make_float4(0.f, 0.f, 0.f, 0.f);
        }
      } else {
        av = *reinterpret_cast<const float4*>(O + ((size_t)b * Tq + t) * Dq + kb + lc);
      }
      As[lc + 0][m] = av.x; As[lc + 1][m] = av.y;
      As[lc + 2][m] = av.z; As[lc + 3][m] = av.w;
    }
    // ---- stage B tile ----
#pragma unroll
    for (int h = 0; h < 2; h++) {
      int n = lr + h * 64;
      int gn = n0 + n;
      const float* wrow;
      int col;
      if (mode == 0) {
        if (gn < 512) { wrow = Wm + (size_t)gn * 2560; col = kb + lc; }
        else          { wrow = Wg + (size_t)(gn - 512) * 3072; col = kb + lc; }
      } else {
        wrow = Wg + (size_t)gn * 3072; col = 2560 + kb + lc;
      }
      float4 bv = *reinterpret_cast<const float4*>(wrow + col);
      Bs[lc + 0][n] = bv.x; Bs[lc + 1][n] = bv.y;
      Bs[lc + 2][n] = bv.z; Bs[lc + 3][n] = bv.w;
    }
    __syncthreads();
#pragma unroll
    for (int kk = 0; kk < BK; kk++) {
      float a[8], bb[8];
      float4 a0 = *reinterpret_cast<float4*>(&As[kk][ty * 8]);
      float4 a1 = *reinterpret_cast<float4*>(&As[kk][ty * 8 + 4]);
      float4 b0 = *reinterpret_cast<float4*>(&Bs[kk][tx * 8]);
      float4 b1 = *reinterpret_cast<float4*>(&Bs[kk][tx * 8 + 4]);
      a[0]=a0.x; a[1]=a0.y; a[2]=a0.z; a[3]=a0.w; a[4]=a1.x; a[5]=a1.y; a[6]=a1.z; a[7]=a1.w;
      bb[0]=b0.x; bb[1]=b0.y; bb[2]=b0.z; bb[3]=b0.w; bb[4]=b1.x; bb[5]=b1.y; bb[6]=b1.z; bb[7]=b1.w;
#pragma unroll
      for (int i = 0; i < 8; i++)
#pragma unroll
        for (int j = 0; j < 8; j++) acc[i][j] = fmaf(a[i], bb[j], acc[i][j]);
    }
    __syncthreads();
  }

  // ---- epilogue ----
  int gn = n0 + tx * 8;
  float bias[8];
  float* dstbase;
  int coloff;
  if (mode == 0) {
    if (gn < 512) {
#pragma unroll
      for (int j = 0; j < 8; j++) bias[j] = bm[gn + j];
      dstbase = Pm; coloff = gn;
    } else {
#pragma unroll
      for (int j = 0; j < 8; j++) bias[j] = bg[gn - 512 + j];
      dstbase = Pg; coloff = gn - 512;
    }
  } else {
#pragma unroll
    for (int j = 0; j < 8; j++) bias[j] = 0.f;
    dstbase = Gm; coloff = gn;
  }
#pragma unroll
  for (int i = 0; i < 8; i++) {
    int bt = bt0 + ty * 8 + i;
    float4 v0 = make_float4(acc[i][0] + bias[0], acc[i][1] + bias[1],
                            acc[i][2] + bias[2], acc[i][3] + bias[3]);
    float4 v1 = make_float4(acc[i][4] + bias[4], acc[i][5] + bias[5],
                            acc[i][6] + bias[6], acc[i][7] + bias[7]);
    float4* d = reinterpret_cast<float4*>(dstbase + (size_t)bt * Dq + coloff);
    d[0] = v0;
    d[1] = v1;
  }
}

extern "C" void kernel_launch(void* const* d_in, const int* in_sizes, int n_in,
                              void* d_out, int out_size, void* d_ws, size_t ws_size,
                              hipStream_t stream) {
  const float* O  = (const float*)d_in[0];  // outputs [8,2048,512]
  const float* Wm = (const float*)d_in[1];  // W_mlp [512,2560]
  const float* bm = (const float*)d_in[2];  // b_mlp [512]
  const float* Wg = (const float*)d_in[3];  // W_gate [512,3072]
  const float* bg = (const float*)d_in[4];  // b_gate [512]
  float* out = (float*)d_out;               // [8,2048,512]; holds PRE_mlp between kernels

  const size_t NTOT = (size_t)Bq * Tq * Dq;  // 8.39M elements
  float* Pg = (float*)d_ws;                  // PRE_gate [8,2048,512]
  float* Gm = Pg + NTOT;                     // G        [8,2048,512]

  // Parallel precompute: PRE_mlp (-> d_out), PRE_gate, G
  gemm_pre<<<dim3(128, 8), dim3(256), 0, stream>>>(O, Wm, Wg, bm, bg, out, Pg, Gm, 0);
  gemm_pre<<<dim3(128, 4), dim3(256), 0, stream>>>(O, Wm, Wg, bm, bg, out, Pg, Gm, 1);

  // Sequential scan: one wave per batch, in-place PRE_mlp -> out.
  scan_kernel<<<dim3(Bq), dim3(64), 0, stream>>>(O, Gm, Pg, out);
}

// Round 2
// 2902.512 us; speedup vs baseline: 1.3556x; 1.3556x over previous
//
#include <hip/hip_runtime.h>

#define Bq 8
#define Tq 2048
#define Dq 512
#define Wq 5

// ---------------------------------------------------------------------------
// DPP-based wave(64) sum, result broadcast to all lanes via readlane->SGPR.
// Sequence: row_shr 1/2/4/8 (per-16 row sums into lane15/31/47/63),
// row_bcast15 (lane15->row1, lane47->row3), row_bcast31 (lane31->upper half).
// Lane 63 ends with the full 64-lane sum. bound_ctrl=true -> invalid lanes = 0.
// ---------------------------------------------------------------------------
template <int CTRL>
__device__ __forceinline__ float dppadd(float v) {
  int r = __builtin_amdgcn_update_dpp(0, __float_as_int(v), CTRL, 0xF, 0xF, true);
  return v + __int_as_float(r);
}
__device__ __forceinline__ float wave_sum_bcast(float v) {
  v = dppadd<0x111>(v);  // row_shr:1
  v = dppadd<0x112>(v);  // row_shr:2
  v = dppadd<0x114>(v);  // row_shr:4
  v = dppadd<0x118>(v);  // row_shr:8
  v = dppadd<0x142>(v);  // row_bcast:15
  v = dppadd<0x143>(v);  // row_bcast:31
  return __int_as_float(__builtin_amdgcn_readlane(__float_as_int(v), 63));
}

__device__ __forceinline__ void load_row8(const float* __restrict__ base, int r,
                                          int lane, float dst[8]) {
  const float4* p = reinterpret_cast<const float4*>(base + (size_t)r * Dq) + lane * 2;
  float4 a = p[0];
  float4 c = p[1];
  dst[0] = a.x; dst[1] = a.y; dst[2] = a.z; dst[3] = a.w;
  dst[4] = c.x; dst[5] = c.y; dst[6] = c.z; dst[7] = c.w;
}

// ---------------------------------------------------------------------------
// One scan step, deep-pipelined. Window rows live in a 10-slot register ring
// (slot = row % 10); pm/pg (per-t precomputed GEMM rows) in 5-slot rings
// (slot = t % 5). At step t we consume this step's data and ISSUE loads for
// window row t+7 (-> slot SLW) and pm/pg row t+5 (-> slot PM, just consumed):
// every load has >= 5 steps of lead time. All ring indices are compile-time.
// S0..S4 = slots holding window rows for j=0..4. m3/m4 mask invalid j (their
// score is forced to exact 0, matching the reference's zero-padded rows; they
// still contribute exp(0) to the softmax denominator, as in the reference).
// ---------------------------------------------------------------------------
template <int S0, int S1, int S2, int S3, int S4, int SLW, int PM>
__device__ __forceinline__ void scan_step(
    int t, float m3, float m4,
    const float* __restrict__ ob, const float* __restrict__ Gb,
    const float* __restrict__ Pgb, float* __restrict__ po,
    float ow[10][8], float gw[10][8], float pm5[5][8], float pg5[5][8],
    float st[8], int lane) {
  // Consume this step's pm/pg into temps (frees the ring slot for refill).
  float pm[8], pg[8];
#pragma unroll
  for (int i = 0; i < 8; i++) { pm[i] = pm5[PM][i]; pg[i] = pg5[PM][i]; }

  // Issue prefetches (state-independent; consumed 5+ steps later).
  int rw = t + 7; if (rw > Tq - 1) rw = Tq - 1;
  int rp = t + 5; if (rp > Tq - 1) rp = Tq - 1;
  load_row8(ob,  rw, lane, ow[SLW]);
  load_row8(Gb,  rw, lane, gw[SLW]);
  load_row8(po,  rp, lane, pm5[PM]);  // po holds PRE_mlp; row rp is read 5 steps
  load_row8(Pgb, rp, lane, pg5[PM]);  // before the scan overwrites it at step rp.

  // scores s_j = state . window_row_j (per-lane partials over 8 dims)
  float s0 = 0.f, s1 = 0.f, s2 = 0.f, s3 = 0.f, s4 = 0.f;
#pragma unroll
  for (int i = 0; i < 8; i++) {
    float sv = st[i];
    s0 = fmaf(sv, ow[S0][i], s0);
    s1 = fmaf(sv, ow[S1][i], s1);
    s2 = fmaf(sv, ow[S2][i], s2);
    s3 = fmaf(sv, ow[S3][i], s3);
    s4 = fmaf(sv, ow[S4][i], s4);
  }
  const float scale = 0.04419417382415922f;  // 1/sqrt(512)
  s0 = wave_sum_bcast(s0) * scale;
  s1 = wave_sum_bcast(s1) * scale;
  s2 = wave_sum_bcast(s2) * scale;
  s3 = wave_sum_bcast(s3) * (scale * m3);  // masked scores -> exact 0
  s4 = wave_sum_bcast(s4) * (scale * m4);

  float mx = fmaxf(fmaxf(fmaxf(s0, s1), fmaxf(s2, s3)), s4);
  float e0 = __expf(s0 - mx), e1 = __expf(s1 - mx), e2 = __expf(s2 - mx);
  float e3 = __expf(s3 - mx), e4 = __expf(s4 - mx);
  float inv = __fdividef(1.0f, e0 + e1 + e2 + e3 + e4);
  float q0 = e0 * inv, q1 = e1 * inv, q2 = e2 * inv;
  float q3 = e3 * inv * m3, q4 = e4 * inv * m4;  // padded rows contribute 0

  float ot[8];
#pragma unroll
  for (int i = 0; i < 8; i++) {
    float at_ = q0 * ow[S0][i] + q1 * ow[S1][i] + q2 * ow[S2][i] +
                q3 * ow[S3][i] + q4 * ow[S4][i];
    float gs_ = q0 * gw[S0][i] + q1 * gw[S1][i] + q2 * gw[S2][i] +
                q3 * gw[S3][i] + q4 * gw[S4][i];
    float x = pg[i] + gs_;
    float gate = __fdividef(1.0f, 1.0f + __expf(-x));
    ot[i] = pm[i] + at_ * gate;
    st[i] = ot[i];
  }
  float4* dst = reinterpret_cast<float4*>(po + (size_t)t * Dq) + lane * 2;
  dst[0] = make_float4(ot[0], ot[1], ot[2], ot[3]);
  dst[1] = make_float4(ot[4], ot[5], ot[6], ot[7]);
}

// ---------------------------------------------------------------------------
// Sequential scan: one block (one wave) per batch. Lane l owns dims [8l,8l+8).
// launch_bounds(64,1): allow max VGPRs (rings ~290 regs), occupancy is moot
// (8 waves total on a 256-CU chip).
// ---------------------------------------------------------------------------
__global__ __launch_bounds__(64, 1) void scan_kernel(
    const float* __restrict__ O, const float* __restrict__ Gm,
    const float* __restrict__ Pg, float* __restrict__ out) {
  int b = blockIdx.x;
  int lane = threadIdx.x;
  const float* ob = O + (size_t)b * Tq * Dq;
  const float* Gb = Gm + (size_t)b * Tq * Dq;
  const float* Pgb = Pg + (size_t)b * Tq * Dq;
  float* po = out + (size_t)b * Tq * Dq;

  float ow[10][8], gw[10][8], pm5[5][8], pg5[5][8], st[8];
#pragma unroll
  for (int i = 0; i < 8; i++) st[i] = 0.f;

  // Prologue: window rows 0..6 -> slots 0..6; pm/pg rows 0..4 -> slots 0..4.
  // (Slots 7,8,9 are written by the prefetches of steps t=0,1,2 before any read.)
#pragma unroll
  for (int r = 0; r < 7; r++) { load_row8(ob, r, lane, ow[r]); load_row8(Gb, r, lane, gw[r]); }
#pragma unroll
  for (int r = 0; r < 5; r++) { load_row8(po, r, lane, pm5[r]); load_row8(Pgb, r, lane, pg5[r]); }

  // t=0: valid rows {0,1,2} (left-edge shift) -> slots 0..2, m3=m4=0.
  scan_step<0, 1, 2, 3, 4, 7, 0>(0, 0.f, 0.f, ob, Gb, Pgb, po, ow, gw, pm5, pg5, st, lane);
  // t=1: valid rows {0..3} -> slots 0..3, m4=0.
  scan_step<0, 1, 2, 3, 4, 8, 1>(1, 1.f, 0.f, ob, Gb, Pgb, po, ow, gw, pm5, pg5, st, lane);

  // Main: t = 2..2041, 204 iterations x 10 statically-phased steps.
  // slot(window row r) = r % 10; slot(pm/pg row t) = t % 5.
  for (int tb = 2; tb <= 2032; tb += 10) {
    scan_step<0, 1, 2, 3, 4, 9, 2>(tb + 0, 1.f, 1.f, ob, Gb, Pgb, po, ow, gw, pm5, pg5, st, lane);
    scan_step<1, 2, 3, 4, 5, 0, 3>(tb + 1, 1.f, 1.f, ob, Gb, Pgb, po, ow, gw, pm5, pg5, st, lane);
    scan_step<2, 3, 4, 5, 6, 1, 4>(tb + 2, 1.f, 1.f, ob, Gb, Pgb, po, ow, gw, pm5, pg5, st, lane);
    scan_step<3, 4, 5, 6, 7, 2, 0>(tb + 3, 1.f, 1.f, ob, Gb, Pgb, po, ow, gw, pm5, pg5, st, lane);
    scan_step<4, 5, 6, 7, 8, 3, 1>(tb + 4, 1.f, 1.f, ob, Gb, Pgb, po, ow, gw, pm5, pg5, st, lane);
    scan_step<5, 6, 7, 8, 9, 4, 2>(tb + 5, 1.f, 1.f, ob, Gb, Pgb, po, ow, gw, pm5, pg5, st, lane);
    scan_step<6, 7, 8, 9, 0, 5, 3>(tb + 6, 1.f, 1.f, ob, Gb, Pgb, po, ow, gw, pm5, pg5, st, lane);
    scan_step<7, 8, 9, 0, 1, 6, 4>(tb + 7, 1.f, 1.f, ob, Gb, Pgb, po, ow, gw, pm5, pg5, st, lane);
    scan_step<8, 9, 0, 1, 2, 7, 0>(tb + 8, 1.f, 1.f, ob, Gb, Pgb, po, ow, gw, pm5, pg5, st, lane);
    scan_step<9, 0, 1, 2, 3, 8, 1>(tb + 9, 1.f, 1.f, ob, Gb, Pgb, po, ow, gw, pm5, pg5, st, lane);
  }
  // Tail: t = 2042..2047 (phases U=0..5). m3 = (t+1<=2047), m4 = (t+2<=2047).
  scan_step<0, 1, 2, 3, 4, 9, 2>(2042, 1.f, 1.f, ob, Gb, Pgb, po, ow, gw, pm5, pg5, st, lane);
  scan_step<1, 2, 3, 4, 5, 0, 3>(2043, 1.f, 1.f, ob, Gb, Pgb, po, ow, gw, pm5, pg5, st, lane);
  scan_step<2, 3, 4, 5, 6, 1, 4>(2044, 1.f, 1.f, ob, Gb, Pgb, po, ow, gw, pm5, pg5, st, lane);
  scan_step<3, 4, 5, 6, 7, 2, 0>(2045, 1.f, 1.f, ob, Gb, Pgb, po, ow, gw, pm5, pg5, st, lane);
  scan_step<4, 5, 6, 7, 8, 3, 1>(2046, 1.f, 0.f, ob, Gb, Pgb, po, ow, gw, pm5, pg5, st, lane);
  scan_step<5, 6, 7, 8, 9, 4, 2>(2047, 0.f, 0.f, ob, Gb, Pgb, po, ow, gw, pm5, pg5, st, lane);
}

// ---------------------------------------------------------------------------
// Precompute GEMMs (unchanged from R1): f32, 128x128x16 tiles, 8x8 microtile.
// mode 0: windowed-A GEMM (K=2560), n<512 -> PRE_mlp(+b_mlp) into d_out,
//         n>=512 -> PRE_gate(+b_gate). mode 1: G = O @ W_gate[:,2560:].T.
// ---------------------------------------------------------------------------
__global__ __launch_bounds__(256) void gemm_pre(
    const float* __restrict__ O, const float* __restrict__ Wm,
    const float* __restrict__ Wg, const float* __restrict__ bm,
    const float* __restrict__ bg, float* __restrict__ Pm,
    float* __restrict__ Pg, float* __restrict__ Gm, int mode) {
  const int BM = 128, BN = 128, BK = 16;
  __shared__ float As[BK][132];
  __shared__ float Bs[BK][132];

  int tidx = threadIdx.x;
  int bt0 = blockIdx.x * BM;
  int b = bt0 / Tq;
  int t0 = bt0 % Tq;
  int n0 = blockIdx.y * BN;
  int K = mode ? Dq : Wq * Dq;

  int tx = tidx % 16;
  int ty = tidx / 16;
  int lr = tidx >> 2;
  int lc = (tidx & 3) * 4;

  float acc[8][8];
#pragma unroll
  for (int i = 0; i < 8; i++)
#pragma unroll
    for (int j = 0; j < 8; j++) acc[i][j] = 0.f;

  for (int kb = 0; kb < K; kb += BK) {
#pragma unroll
    for (int h = 0; h < 2; h++) {
      int m = lr + h * 64;
      int t = t0 + m;
      float4 av;
      if (mode == 0) {
        int j = kb >> 9;
        int kcol = (kb & 511) + lc;
        int sh = 2 - t; if (sh < 0) sh = 0;
        int r = t - 2 + j + sh;
        int hi = t + 2; if (hi > Tq - 1) hi = Tq - 1;
        int lo = t - 2; if (lo < 0) lo = 0;
        int nv = hi - lo + 1;
        if (j < nv) {
          av = *reinterpret_cast<const float4*>(O + ((size_t)b * Tq + r) * Dq + kcol);
        } else {
          av = make_float4(0.f, 0.f, 0.f, 0.f);
        }
      } else {
        av = *reinterpret_cast<const float4*>(O + ((size_t)b * Tq + t) * Dq + kb + lc);
      }
      As[lc + 0][m] = av.x; As[lc + 1][m] = av.y;
      As[lc + 2][m] = av.z; As[lc + 3][m] = av.w;
    }
#pragma unroll
    for (int h = 0; h < 2; h++) {
      int n = lr + h * 64;
      int gn = n0 + n;
      const float* wrow;
      int col;
      if (mode == 0) {
        if (gn < 512) { wrow = Wm + (size_t)gn * 2560; col = kb + lc; }
        else          { wrow = Wg + (size_t)(gn - 512) * 3072; col = kb + lc; }
      } else {
        wrow = Wg + (size_t)gn * 3072; col = 2560 + kb + lc;
      }
      float4 bv = *reinterpret_cast<const float4*>(wrow + col);
      Bs[lc + 0][n] = bv.x; Bs[lc + 1][n] = bv.y;
      Bs[lc + 2][n] = bv.z; Bs[lc + 3][n] = bv.w;
    }
    __syncthreads();
#pragma unroll
    for (int kk = 0; kk < BK; kk++) {
      float a[8], bb[8];
      float4 a0 = *reinterpret_cast<float4*>(&As[kk][ty * 8]);
      float4 a1 = *reinterpret_cast<float4*>(&As[kk][ty * 8 + 4]);
      float4 b0 = *reinterpret_cast<float4*>(&Bs[kk][tx * 8]);
      float4 b1 = *reinterpret_cast<float4*>(&Bs[kk][tx * 8 + 4]);
      a[0]=a0.x; a[1]=a0.y; a[2]=a0.z; a[3]=a0.w; a[4]=a1.x; a[5]=a1.y; a[6]=a1.z; a[7]=a1.w;
      bb[0]=b0.x; bb[1]=b0.y; bb[2]=b0.z; bb[3]=b0.w; bb[4]=b1.x; bb[5]=b1.y; bb[6]=b1.z; bb[7]=b1.w;
#pragma unroll
      for (int i = 0; i < 8; i++)
#pragma unroll
        for (int j = 0; j < 8; j++) acc[i][j] = fmaf(a[i], bb[j], acc[i][j]);
    }
    __syncthreads();
  }

  int gn = n0 + tx * 8;
  float bias[8];
  float* dstbase;
  int coloff;
  if (mode == 0) {
    if (gn < 512) {
#pragma unroll
      for (int j = 0; j < 8; j++) bias[j] = bm[gn + j];
      dstbase = Pm; coloff = gn;
    } else {
#pragma unroll
      for (int j = 0; j < 8; j++) bias[j] = bg[gn - 512 + j];
      dstbase = Pg; coloff = gn - 512;
    }
  } else {
#pragma unroll
    for (int j = 0; j < 8; j++) bias[j] = 0.f;
    dstbase = Gm; coloff = gn;
  }
#pragma unroll
  for (int i = 0; i < 8; i++) {
    int bt = bt0 + ty * 8 + i;
    float4 v0 = make_float4(acc[i][0] + bias[0], acc[i][1] + bias[1],
                            acc[i][2] + bias[2], acc[i][3] + bias[3]);
    float4 v1 = make_float4(acc[i][4] + bias[4], acc[i][5] + bias[5],
                            acc[i][6] + bias[6], acc[i][7] + bias[7]);
    float4* d = reinterpret_cast<float4*>(dstbase + (size_t)bt * Dq + coloff);
    d[0] = v0;
    d[1] = v1;
  }
}

extern "C" void kernel_launch(void* const* d_in, const int* in_sizes, int n_in,
                              void* d_out, int out_size, void* d_ws, size_t ws_size,
                              hipStream_t stream) {
  const float* O  = (const float*)d_in[0];  // outputs [8,2048,512]
  const float* Wm = (const float*)d_in[1];  // W_mlp [512,2560]
  const float* bm = (const float*)d_in[2];  // b_mlp [512]
  const float* Wg = (const float*)d_in[3];  // W_gate [512,3072]
  const float* bg = (const float*)d_in[4];  // b_gate [512]
  float* out = (float*)d_out;               // [8,2048,512]; holds PRE_mlp between kernels

  const size_t NTOT = (size_t)Bq * Tq * Dq;
  float* Pg = (float*)d_ws;                  // PRE_gate [8,2048,512]
  float* Gm = Pg + NTOT;                     // G        [8,2048,512]

  gemm_pre<<<dim3(128, 8), dim3(256), 0, stream>>>(O, Wm, Wg, bm, bg, out, Pg, Gm, 0);
  gemm_pre<<<dim3(128, 4), dim3(256), 0, stream>>>(O, Wm, Wg, bm, bg, out, Pg, Gm, 1);

  scan_kernel<<<dim3(Bq), dim3(64), 0, stream>>>(O, Gm, Pg, out);
}

// Round 3
// 2877.343 us; speedup vs baseline: 1.3674x; 1.0087x over previous
//
#include <hip/hip_runtime.h>

#define Bq 8
#define Tq 2048
#define Dq 512
#define Wq 5

// ---------------------------------------------------------------------------
// DPP-based wave(64) sum, result broadcast to all lanes via readlane->SGPR.
// row_shr 1/2/4/8 + row_bcast:15 + row_bcast:31; lane 63 holds the total.
// ---------------------------------------------------------------------------
template <int CTRL>
__device__ __forceinline__ float dppadd(float v) {
  int r = __builtin_amdgcn_update_dpp(0, __float_as_int(v), CTRL, 0xF, 0xF, true);
  return v + __int_as_float(r);
}
__device__ __forceinline__ float wave_sum_bcast(float v) {
  v = dppadd<0x111>(v);  // row_shr:1
  v = dppadd<0x112>(v);  // row_shr:2
  v = dppadd<0x114>(v);  // row_shr:4
  v = dppadd<0x118>(v);  // row_shr:8
  v = dppadd<0x142>(v);  // row_bcast:15
  v = dppadd<0x143>(v);  // row_bcast:31
  return __int_as_float(__builtin_amdgcn_readlane(__float_as_int(v), 63));
}

__device__ __forceinline__ void load_row8(const float* __restrict__ base, int r,
                                          int lane, float dst[8]) {
  const float4* p = reinterpret_cast<const float4*>(base + (size_t)r * Dq) + lane * 2;
  float4 a = p[0];
  float4 c = p[1];
  dst[0] = a.x; dst[1] = a.y; dst[2] = a.z; dst[3] = a.w;
  dst[4] = c.x; dst[5] = c.y; dst[6] = c.z; dst[7] = c.w;
}

// ---------------------------------------------------------------------------
// One scan step, deep-pipelined (see R2 comments). pmb = PRE_mlp base, which
// is a DISTINCT buffer from the output po when ws allows: po becomes
// store-only, so prefetch loads never need ordering against stores.
// ---------------------------------------------------------------------------
template <int S0, int S1, int S2, int S3, int S4, int SLW, int PM>
__device__ __forceinline__ void scan_step(
    int t, float m3, float m4,
    const float* __restrict__ ob, const float* __restrict__ Gb,
    const float* __restrict__ Pgb, const float* __restrict__ pmb,
    float* __restrict__ po,
    float ow[10][8], float gw[10][8], float pm5[5][8], float pg5[5][8],
    float st[8], int lane) {
  // Consume this step's pm/pg into temps (frees the ring slot for refill).
  float pm[8], pg[8];
#pragma unroll
  for (int i = 0; i < 8; i++) { pm[i] = pm5[PM][i]; pg[i] = pg5[PM][i]; }

  // Issue prefetches (state-independent; consumed 5+ steps later).
  int rw = t + 7; if (rw > Tq - 1) rw = Tq - 1;
  int rp = t + 5; if (rp > Tq - 1) rp = Tq - 1;
  load_row8(ob,  rw, lane, ow[SLW]);
  load_row8(Gb,  rw, lane, gw[SLW]);
  load_row8(pmb, rp, lane, pm5[PM]);
  load_row8(Pgb, rp, lane, pg5[PM]);

  // scores s_j = state . window_row_j (per-lane partials over 8 dims)
  float s0 = 0.f, s1 = 0.f, s2 = 0.f, s3 = 0.f, s4 = 0.f;
#pragma unroll
  for (int i = 0; i < 8; i++) {
    float sv = st[i];
    s0 = fmaf(sv, ow[S0][i], s0);
    s1 = fmaf(sv, ow[S1][i], s1);
    s2 = fmaf(sv, ow[S2][i], s2);
    s3 = fmaf(sv, ow[S3][i], s3);
    s4 = fmaf(sv, ow[S4][i], s4);
  }
  const float scale = 0.04419417382415922f;  // 1/sqrt(512)
  s0 = wave_sum_bcast(s0) * scale;
  s1 = wave_sum_bcast(s1) * scale;
  s2 = wave_sum_bcast(s2) * scale;
  s3 = wave_sum_bcast(s3) * (scale * m3);  // masked scores -> exact 0
  s4 = wave_sum_bcast(s4) * (scale * m4);

  float mx = fmaxf(fmaxf(fmaxf(s0, s1), fmaxf(s2, s3)), s4);
  float e0 = __expf(s0 - mx), e1 = __expf(s1 - mx), e2 = __expf(s2 - mx);
  float e3 = __expf(s3 - mx), e4 = __expf(s4 - mx);
  float inv = __fdividef(1.0f, e0 + e1 + e2 + e3 + e4);
  float q0 = e0 * inv, q1 = e1 * inv, q2 = e2 * inv;
  float q3 = e3 * inv * m3, q4 = e4 * inv * m4;  // padded rows contribute 0

  float ot[8];
#pragma unroll
  for (int i = 0; i < 8; i++) {
    float at_ = q0 * ow[S0][i] + q1 * ow[S1][i] + q2 * ow[S2][i] +
                q3 * ow[S3][i] + q4 * ow[S4][i];
    float gs_ = q0 * gw[S0][i] + q1 * gw[S1][i] + q2 * gw[S2][i] +
                q3 * gw[S3][i] + q4 * gw[S4][i];
    float x = pg[i] + gs_;
    float gate = __fdividef(1.0f, 1.0f + __expf(-x));
    ot[i] = pm[i] + at_ * gate;
    st[i] = ot[i];
  }
  float4* dst = reinterpret_cast<float4*>(po + (size_t)t * Dq) + lane * 2;
  dst[0] = make_float4(ot[0], ot[1], ot[2], ot[3]);
  dst[1] = make_float4(ot[4], ot[5], ot[6], ot[7]);
}

// ---------------------------------------------------------------------------
// Sequential scan: one block (one wave) per batch. Lane l owns dims [8l,8l+8).
// Pm may be a separate ws buffer (fast path: po is store-only) or equal to
// out (fallback, R2-identical behavior).
// ---------------------------------------------------------------------------
__global__ __launch_bounds__(64, 1) void scan_kernel(
    const float* __restrict__ O, const float* __restrict__ Gm,
    const float* __restrict__ Pg, const float* __restrict__ Pm,
    float* __restrict__ out) {
  int b = blockIdx.x;
  int lane = threadIdx.x;
  const float* ob = O + (size_t)b * Tq * Dq;
  const float* Gb = Gm + (size_t)b * Tq * Dq;
  const float* Pgb = Pg + (size_t)b * Tq * Dq;
  const float* pmb = Pm + (size_t)b * Tq * Dq;
  float* po = out + (size_t)b * Tq * Dq;

  float ow[10][8], gw[10][8], pm5[5][8], pg5[5][8], st[8];
#pragma unroll
  for (int i = 0; i < 8; i++) st[i] = 0.f;

  // Prologue: window rows 0..6 -> slots 0..6; pm/pg rows 0..4 -> slots 0..4.
#pragma unroll
  for (int r = 0; r < 7; r++) { load_row8(ob, r, lane, ow[r]); load_row8(Gb, r, lane, gw[r]); }
#pragma unroll
  for (int r = 0; r < 5; r++) { load_row8(pmb, r, lane, pm5[r]); load_row8(Pgb, r, lane, pg5[r]); }

  // t=0: valid rows {0,1,2}, m3=m4=0.  t=1: valid rows {0..3}, m4=0.
  scan_step<0, 1, 2, 3, 4, 7, 0>(0, 0.f, 0.f, ob, Gb, Pgb, pmb, po, ow, gw, pm5, pg5, st, lane);
  scan_step<0, 1, 2, 3, 4, 8, 1>(1, 1.f, 0.f, ob, Gb, Pgb, pmb, po, ow, gw, pm5, pg5, st, lane);

  // Main: t = 2..2041, 204 iterations x 10 statically-phased steps.
  // slot(window row r) = r % 10; slot(pm/pg row t) = t % 5.
  for (int tb = 2; tb <= 2032; tb += 10) {
    scan_step<0, 1, 2, 3, 4, 9, 2>(tb + 0, 1.f, 1.f, ob, Gb, Pgb, pmb, po, ow, gw, pm5, pg5, st, lane);
    scan_step<1, 2, 3, 4, 5, 0, 3>(tb + 1, 1.f, 1.f, ob, Gb, Pgb, pmb, po, ow, gw, pm5, pg5, st, lane);
    scan_step<2, 3, 4, 5, 6, 1, 4>(tb + 2, 1.f, 1.f, ob, Gb, Pgb, pmb, po, ow, gw, pm5, pg5, st, lane);
    scan_step<3, 4, 5, 6, 7, 2, 0>(tb + 3, 1.f, 1.f, ob, Gb, Pgb, pmb, po, ow, gw, pm5, pg5, st, lane);
    scan_step<4, 5, 6, 7, 8, 3, 1>(tb + 4, 1.f, 1.f, ob, Gb, Pgb, pmb, po, ow, gw, pm5, pg5, st, lane);
    scan_step<5, 6, 7, 8, 9, 4, 2>(tb + 5, 1.f, 1.f, ob, Gb, Pgb, pmb, po, ow, gw, pm5, pg5, st, lane);
    scan_step<6, 7, 8, 9, 0, 5, 3>(tb + 6, 1.f, 1.f, ob, Gb, Pgb, pmb, po, ow, gw, pm5, pg5, st, lane);
    scan_step<7, 8, 9, 0, 1, 6, 4>(tb + 7, 1.f, 1.f, ob, Gb, Pgb, pmb, po, ow, gw, pm5, pg5, st, lane);
    scan_step<8, 9, 0, 1, 2, 7, 0>(tb + 8, 1.f, 1.f, ob, Gb, Pgb, pmb, po, ow, gw, pm5, pg5, st, lane);
    scan_step<9, 0, 1, 2, 3, 8, 1>(tb + 9, 1.f, 1.f, ob, Gb, Pgb, pmb, po, ow, gw, pm5, pg5, st, lane);
  }
  // Tail: t = 2042..2047. m3 = (t+1<=2047), m4 = (t+2<=2047).
  scan_step<0, 1, 2, 3, 4, 9, 2>(2042, 1.f, 1.f, ob, Gb, Pgb, pmb, po, ow, gw, pm5, pg5, st, lane);
  scan_step<1, 2, 3, 4, 5, 0, 3>(2043, 1.f, 1.f, ob, Gb, Pgb, pmb, po, ow, gw, pm5, pg5, st, lane);
  scan_step<2, 3, 4, 5, 6, 1, 4>(2044, 1.f, 1.f, ob, Gb, Pgb, pmb, po, ow, gw, pm5, pg5, st, lane);
  scan_step<3, 4, 5, 6, 7, 2, 0>(2045, 1.f, 1.f, ob, Gb, Pgb, pmb, po, ow, gw, pm5, pg5, st, lane);
  scan_step<4, 5, 6, 7, 8, 3, 1>(2046, 1.f, 0.f, ob, Gb, Pgb, pmb, po, ow, gw, pm5, pg5, st, lane);
  scan_step<5, 6, 7, 8, 9, 4, 2>(2047, 0.f, 0.f, ob, Gb, Pgb, pmb, po, ow, gw, pm5, pg5, st, lane);
}

// ---------------------------------------------------------------------------
// Precompute GEMMs (unchanged): f32, 128x128x16 tiles, 8x8 microtile.
// mode 0: windowed-A GEMM (K=2560), n<512 -> PRE_mlp(+b_mlp) into Pm,
//         n>=512 -> PRE_gate(+b_gate). mode 1: G = O @ W_gate[:,2560:].T.
// ---------------------------------------------------------------------------
__global__ __launch_bounds__(256) void gemm_pre(
    const float* __restrict__ O, const float* __restrict__ Wm,
    const float* __restrict__ Wg, const float* __restrict__ bm,
    const float* __restrict__ bg, float* __restrict__ Pm,
    float* __restrict__ Pg, float* __restrict__ Gm, int mode) {
  const int BM = 128, BN = 128, BK = 16;
  __shared__ float As[BK][132];
  __shared__ float Bs[BK][132];

  int tidx = threadIdx.x;
  int bt0 = blockIdx.x * BM;
  int b = bt0 / Tq;
  int t0 = bt0 % Tq;
  int n0 = blockIdx.y * BN;
  int K = mode ? Dq : Wq * Dq;

  int tx = tidx % 16;
  int ty = tidx / 16;
  int lr = tidx >> 2;
  int lc = (tidx & 3) * 4;

  float acc[8][8];
#pragma unroll
  for (int i = 0; i < 8; i++)
#pragma unroll
    for (int j = 0; j < 8; j++) acc[i][j] = 0.f;

  for (int kb = 0; kb < K; kb += BK) {
#pragma unroll
    for (int h = 0; h < 2; h++) {
      int m = lr + h * 64;
      int t = t0 + m;
      float4 av;
      if (mode == 0) {
        int j = kb >> 9;
        int kcol = (kb & 511) + lc;
        int sh = 2 - t; if (sh < 0) sh = 0;
        int r = t - 2 + j + sh;
        int hi = t + 2; if (hi > Tq - 1) hi = Tq - 1;
        int lo = t - 2; if (lo < 0) lo = 0;
        int nv = hi - lo + 1;
        if (j < nv) {
          av = *reinterpret_cast<const float4*>(O + ((size_t)b * Tq + r) * Dq + kcol);
        } else {
          av = make_float4(0.f, 0.f, 0.f, 0.f);
        }
      } else {
        av = *reinterpret_cast<const float4*>(O + ((size_t)b * Tq + t) * Dq + kb + lc);
      }
      As[lc + 0][m] = av.x; As[lc + 1][m] = av.y;
      As[lc + 2][m] = av.z; As[lc + 3][m] = av.w;
    }
#pragma unroll
    for (int h = 0; h < 2; h++) {
      int n = lr + h * 64;
      int gn = n0 + n;
      const float* wrow;
      int col;
      if (mode == 0) {
        if (gn < 512) { wrow = Wm + (size_t)gn * 2560; col = kb + lc; }
        else          { wrow = Wg + (size_t)(gn - 512) * 3072; col = kb + lc; }
      } else {
        wrow = Wg + (size_t)gn * 3072; col = 2560 + kb + lc;
      }
      float4 bv = *reinterpret_cast<const float4*>(wrow + col);
      Bs[lc + 0][n] = bv.x; Bs[lc + 1][n] = bv.y;
      Bs[lc + 2][n] = bv.z; Bs[lc + 3][n] = bv.w;
    }
    __syncthreads();
#pragma unroll
    for (int kk = 0; kk < BK; kk++) {
      float a[8], bb[8];
      float4 a0 = *reinterpret_cast<float4*>(&As[kk][ty * 8]);
      float4 a1 = *reinterpret_cast<float4*>(&As[kk][ty * 8 + 4]);
      float4 b0 = *reinterpret_cast<float4*>(&Bs[kk][tx * 8]);
      float4 b1 = *reinterpret_cast<float4*>(&Bs[kk][tx * 8 + 4]);
      a[0]=a0.x; a[1]=a0.y; a[2]=a0.z; a[3]=a0.w; a[4]=a1.x; a[5]=a1.y; a[6]=a1.z; a[7]=a1.w;
      bb[0]=b0.x; bb[1]=b0.y; bb[2]=b0.z; bb[3]=b0.w; bb[4]=b1.x; bb[5]=b1.y; bb[6]=b1.z; bb[7]=b1.w;
#pragma unroll
      for (int i = 0; i < 8; i++)
#pragma unroll
        for (int j = 0; j < 8; j++) acc[i][j] = fmaf(a[i], bb[j], acc[i][j]);
    }
    __syncthreads();
  }

  int gn = n0 + tx * 8;
  float bias[8];
  float* dstbase;
  int coloff;
  if (mode == 0) {
    if (gn < 512) {
#pragma unroll
      for (int j = 0; j < 8; j++) bias[j] = bm[gn + j];
      dstbase = Pm; coloff = gn;
    } else {
#pragma unroll
      for (int j = 0; j < 8; j++) bias[j] = bg[gn - 512 + j];
      dstbase = Pg; coloff = gn - 512;
    }
  } else {
#pragma unroll
    for (int j = 0; j < 8; j++) bias[j] = 0.f;
    dstbase = Gm; coloff = gn;
  }
#pragma unroll
  for (int i = 0; i < 8; i++) {
    int bt = bt0 + ty * 8 + i;
    float4 v0 = make_float4(acc[i][0] + bias[0], acc[i][1] + bias[1],
                            acc[i][2] + bias[2], acc[i][3] + bias[3]);
    float4 v1 = make_float4(acc[i][4] + bias[4], acc[i][5] + bias[5],
                            acc[i][6] + bias[6], acc[i][7] + bias[7]);
    float4* d = reinterpret_cast<float4*>(dstbase + (size_t)bt * Dq + coloff);
    d[0] = v0;
    d[1] = v1;
  }
}

extern "C" void kernel_launch(void* const* d_in, const int* in_sizes, int n_in,
                              void* d_out, int out_size, void* d_ws, size_t ws_size,
                              hipStream_t stream) {
  const float* O  = (const float*)d_in[0];  // outputs [8,2048,512]
  const float* Wm = (const float*)d_in[1];  // W_mlp [512,2560]
  const float* bm = (const float*)d_in[2];  // b_mlp [512]
  const float* Wg = (const float*)d_in[3];  // W_gate [512,3072]
  const float* bg = (const float*)d_in[4];  // b_gate [512]
  float* out = (float*)d_out;               // [8,2048,512]

  const size_t NTOT = (size_t)Bq * Tq * Dq;  // 8.39M elements
  float* Pg = (float*)d_ws;                  // PRE_gate [8,2048,512]
  float* Gm = Pg + NTOT;                     // G        [8,2048,512]
  // Fast path: PRE_mlp gets its own ws buffer so the scan's output buffer is
  // store-only (no load/store aliasing -> prefetch pipeline stays full).
  bool sep = ws_size >= (size_t)3 * NTOT * sizeof(float);
  float* Pm = sep ? (Gm + NTOT) : out;

  gemm_pre<<<dim3(128, 8), dim3(256), 0, stream>>>(O, Wm, Wg, bm, bg, Pm, Pg, Gm, 0);
  gemm_pre<<<dim3(128, 4), dim3(256), 0, stream>>>(O, Wm, Wg, bm, bg, Pm, Pg, Gm, 1);

  scan_kernel<<<dim3(Bq), dim3(64), 0, stream>>>(O, Gm, Pg, Pm, out);
}

// Round 4
// 2779.352 us; speedup vs baseline: 1.4156x; 1.0353x over previous
//
#include <hip/hip_runtime.h>

#define Bq 8
#define Tq 2048
#define Dq 512

// ---------------------------------------------------------------------------
// DPP-based wave(64) sum, broadcast to all lanes via readlane(63) -> SGPR.
// ---------------------------------------------------------------------------
template <int CTRL>
__device__ __forceinline__ float dppadd(float v) {
  int r = __builtin_amdgcn_update_dpp(0, __float_as_int(v), CTRL, 0xF, 0xF, true);
  return v + __int_as_float(r);
}
__device__ __forceinline__ float wave_sum_bcast(float v) {
  v = dppadd<0x111>(v);  // row_shr:1
  v = dppadd<0x112>(v);  // row_shr:2
  v = dppadd<0x114>(v);  // row_shr:4
  v = dppadd<0x118>(v);  // row_shr:8
  v = dppadd<0x142>(v);  // row_bcast:15
  v = dppadd<0x143>(v);  // row_bcast:31
  return __int_as_float(__builtin_amdgcn_readlane(__float_as_int(v), 63));
}

// Ownership: lane l owns dims [4l,4l+4) ("A" half) and [256+4l,256+4l+4) ("B").
// Both global and LDS accesses are then 64-lane x 16B contiguous (canonical).
__device__ __forceinline__ void load_row(const float* __restrict__ base, int r,
                                         int lane, float4& a, float4& b) {
  const float* p = base + (size_t)r * Dq + lane * 4;
  a = *reinterpret_cast<const float4*>(p);
  b = *reinterpret_cast<const float4*>(p + 256);
}

__device__ __forceinline__ float dot8(const float4& xa, const float4& xb,
                                      const float4& ya, const float4& yb) {
  float s = xa.x * ya.x;
  s = fmaf(xa.y, ya.y, s);
  s = fmaf(xa.z, ya.z, s);
  s = fmaf(xa.w, ya.w, s);
  s = fmaf(xb.x, yb.x, s);
  s = fmaf(xb.y, yb.y, s);
  s = fmaf(xb.z, yb.z, s);
  s = fmaf(xb.w, yb.w, s);
  return s;
}

__device__ __forceinline__ float4 gate_out(const float4& pm, const float4& pg,
                                           const float4& at, const float4& gs) {
  float4 o;
  o.x = fmaf(at.x, __fdividef(1.f, 1.f + __expf(-(pg.x + gs.x))), pm.x);
  o.y = fmaf(at.y, __fdividef(1.f, 1.f + __expf(-(pg.y + gs.y))), pm.y);
  o.z = fmaf(at.z, __fdividef(1.f, 1.f + __expf(-(pg.z + gs.z))), pm.z);
  o.w = fmaf(at.w, __fdividef(1.f, 1.f + __expf(-(pg.w + gs.w))), pm.w);
  return o;
}

#define WSUM4(dst, arr)                                                        \
  dst.x = q0 * arr[S0].x + q1 * arr[S1].x + q2 * arr[S2].x + q3 * arr[S3].x +  \
          q4 * arr[S4].x;                                                      \
  dst.y = q0 * arr[S0].y + q1 * arr[S1].y + q2 * arr[S2].y + q3 * arr[S3].y +  \
          q4 * arr[S4].y;                                                      \
  dst.z = q0 * arr[S0].z + q1 * arr[S1].z + q2 * arr[S2].z + q3 * arr[S3].z +  \
          q4 * arr[S4].z;                                                      \
  dst.w = q0 * arr[S0].w + q1 * arr[S1].w + q2 * arr[S2].w + q3 * arr[S3].w +  \
          q4 * arr[S4].w;

// ---------------------------------------------------------------------------
// One scan step. All four streams live in 8-slot register rings (slot = row&7
// for window rows; slot = t&7 for pm/pg). Prefetch lead = 5 rows, pinned at
// the top of the step by sched_barrier(0) so the scheduler cannot sink the
// loads to their uses. Output goes to an LDS ring (slot = t&7); every 8th
// step (FLUSH) the 8 completed rows are stored to global in one coalesced
// burst — keeping stores out of the per-step vmcnt stream so register reuse
// never drains the load pipeline. m3/m4 mask invalid window entries (their
// score is forced to exact 0, matching the reference's zero-padded rows).
// ---------------------------------------------------------------------------
template <int S0, int S1, int S2, int S3, int S4, int SLOT, int SLW, bool FLUSH>
__device__ __forceinline__ void scan_step(
    int t, float m3, float m4,
    const float* __restrict__ ob, const float* __restrict__ Gb,
    const float* __restrict__ Pgb, const float* __restrict__ pmb,
    float* __restrict__ po,
    float4 (&owA)[8], float4 (&owB)[8], float4 (&gwA)[8], float4 (&gwB)[8],
    float4 (&pmA)[8], float4 (&pmB)[8], float4 (&pgA)[8], float4 (&pgB)[8],
    float4& stA, float4& stB, int lane, float (*outl)[Dq]) {
  // ---- prefetch row t+5 for all 4 streams (16 dwordx4 loads), pinned ----
  int rw = t + 5; if (rw > Tq - 1) rw = Tq - 1;
  load_row(ob,  rw, lane, owA[SLW], owB[SLW]);
  load_row(Gb,  rw, lane, gwA[SLW], gwB[SLW]);
  load_row(pmb, rw, lane, pmA[SLW], pmB[SLW]);
  load_row(Pgb, rw, lane, pgA[SLW], pgB[SLW]);
  __builtin_amdgcn_sched_barrier(0);

  // ---- scores s_j = state . window_row_j ----
  float s0 = dot8(stA, stB, owA[S0], owB[S0]);
  float s1 = dot8(stA, stB, owA[S1], owB[S1]);
  float s2 = dot8(stA, stB, owA[S2], owB[S2]);
  float s3 = dot8(stA, stB, owA[S3], owB[S3]);
  float s4 = dot8(stA, stB, owA[S4], owB[S4]);
  const float scale = 0.04419417382415922f;  // 1/sqrt(512)
  s0 = wave_sum_bcast(s0) * scale;
  s1 = wave_sum_bcast(s1) * scale;
  s2 = wave_sum_bcast(s2) * scale;
  s3 = wave_sum_bcast(s3) * (scale * m3);
  s4 = wave_sum_bcast(s4) * (scale * m4);

  float mx = fmaxf(fmaxf(fmaxf(s0, s1), fmaxf(s2, s3)), s4);
  float e0 = __expf(s0 - mx), e1 = __expf(s1 - mx), e2 = __expf(s2 - mx);
  float e3 = __expf(s3 - mx), e4 = __expf(s4 - mx);
  float inv = __fdividef(1.0f, e0 + e1 + e2 + e3 + e4);
  float q0 = e0 * inv, q1 = e1 * inv, q2 = e2 * inv;
  float q3 = e3 * inv * m3, q4 = e4 * inv * m4;  // padded rows contribute 0

  // ---- attn / gate-contrib weighted sums ----
  float4 atA, atB, gsA, gsB;
  WSUM4(atA, owA); WSUM4(atB, owB);
  WSUM4(gsA, gwA); WSUM4(gsB, gwB);

  // ---- gate, output, state update ----
  stA = gate_out(pmA[SLOT], pgA[SLOT], atA, gsA);
  stB = gate_out(pmB[SLOT], pgB[SLOT], atB, gsB);

  // ---- stage output row into LDS ring ----
  reinterpret_cast<float4*>(&outl[SLOT][0])[lane] = stA;
  reinterpret_cast<float4*>(&outl[SLOT][256])[lane] = stB;

  // ---- every 8 steps: flush 8 rows LDS -> global (coalesced) ----
  if (FLUSH) {
#pragma unroll
    for (int s = 0; s < 8; s++) {
      float4 va = reinterpret_cast<float4*>(&outl[s][0])[lane];
      float4 vb = reinterpret_cast<float4*>(&outl[s][256])[lane];
      float* dst = po + (size_t)(t - 7 + s) * Dq + lane * 4;
      *reinterpret_cast<float4*>(dst) = va;
      *reinterpret_cast<float4*>(dst + 256) = vb;
    }
  }
}

// ---------------------------------------------------------------------------
// Sequential scan: one block (one wave) per batch. 8 blocks total.
// ---------------------------------------------------------------------------
__global__ __launch_bounds__(64, 1) void scan_kernel(
    const float* __restrict__ O, const float* __restrict__ Gm,
    const float* __restrict__ Pg, const float* __restrict__ Pm,
    float* __restrict__ out) {
  __shared__ float outl[8][Dq];  // 16 KiB output staging ring
  int b = blockIdx.x;
  int lane = threadIdx.x;
  const float* ob  = O  + (size_t)b * Tq * Dq;
  const float* Gb  = Gm + (size_t)b * Tq * Dq;
  const float* Pgb = Pg + (size_t)b * Tq * Dq;
  const float* pmb = Pm + (size_t)b * Tq * Dq;
  float* po = out + (size_t)b * Tq * Dq;

  float4 owA[8], owB[8], gwA[8], gwB[8], pmA[8], pmB[8], pgA[8], pgB[8];
  float4 stA = make_float4(0.f, 0.f, 0.f, 0.f);
  float4 stB = make_float4(0.f, 0.f, 0.f, 0.f);

  // Prologue: rows 0..4 -> slots 0..4 for all four streams.
#pragma unroll
  for (int r = 0; r < 5; r++) {
    load_row(ob,  r, lane, owA[r], owB[r]);
    load_row(Gb,  r, lane, gwA[r], gwB[r]);
    load_row(pmb, r, lane, pmA[r], pmB[r]);
    load_row(Pgb, r, lane, pgA[r], pgB[r]);
  }

  // t=0: window rows {0,1,2} (slots 0..2), m3=m4=0.  t=1: rows {0..3}, m4=0.
  scan_step<0,1,2,3,4, 0, 5, false>(0, 0.f, 0.f, ob, Gb, Pgb, pmb, po,
      owA,owB,gwA,gwB,pmA,pmB,pgA,pgB, stA,stB, lane, outl);
  scan_step<0,1,2,3,4, 1, 6, false>(1, 1.f, 0.f, ob, Gb, Pgb, pmb, po,
      owA,owB,gwA,gwB,pmA,pmB,pgA,pgB, stA,stB, lane, outl);

  // Main: t = 2..2041 = 255 iterations x 8 statically-phased steps.
  // slot(window row r) = r&7; slot(pm/pg/out row t) = t&7; prefetch row t+5.
  for (int tb = 2; tb <= 2034; tb += 8) {
    scan_step<0,1,2,3,4, 2, 7, false>(tb+0, 1.f, 1.f, ob, Gb, Pgb, pmb, po,
        owA,owB,gwA,gwB,pmA,pmB,pgA,pgB, stA,stB, lane, outl);
    scan_step<1,2,3,4,5, 3, 0, false>(tb+1, 1.f, 1.f, ob, Gb, Pgb, pmb, po,
        owA,owB,gwA,gwB,pmA,pmB,pgA,pgB, stA,stB, lane, outl);
    scan_step<2,3,4,5,6, 4, 1, false>(tb+2, 1.f, 1.f, ob, Gb, Pgb, pmb, po,
        owA,owB,gwA,gwB,pmA,pmB,pgA,pgB, stA,stB, lane, outl);
    scan_step<3,4,5,6,7, 5, 2, false>(tb+3, 1.f, 1.f, ob, Gb, Pgb, pmb, po,
        owA,owB,gwA,gwB,pmA,pmB,pgA,pgB, stA,stB, lane, outl);
    scan_step<4,5,6,7,0, 6, 3, false>(tb+4, 1.f, 1.f, ob, Gb, Pgb, pmb, po,
        owA,owB,gwA,gwB,pmA,pmB,pgA,pgB, stA,stB, lane, outl);
    scan_step<5,6,7,0,1, 7, 4, true >(tb+5, 1.f, 1.f, ob, Gb, Pgb, pmb, po,
        owA,owB,gwA,gwB,pmA,pmB,pgA,pgB, stA,stB, lane, outl);
    scan_step<6,7,0,1,2, 0, 5, false>(tb+6, 1.f, 1.f, ob, Gb, Pgb, pmb, po,
        owA,owB,gwA,gwB,pmA,pmB,pgA,pgB, stA,stB, lane, outl);
    scan_step<7,0,1,2,3, 1, 6, false>(tb+7, 1.f, 1.f, ob, Gb, Pgb, pmb, po,
        owA,owB,gwA,gwB,pmA,pmB,pgA,pgB, stA,stB, lane, outl);
  }
  // Tail: t = 2042..2047 (phases t&7 = 2..7). m3=(t+1<=2047), m4=(t+2<=2047).
  scan_step<0,1,2,3,4, 2, 7, false>(2042, 1.f, 1.f, ob, Gb, Pgb, pmb, po,
      owA,owB,gwA,gwB,pmA,pmB,pgA,pgB, stA,stB, lane, outl);
  scan_step<1,2,3,4,5, 3, 0, false>(2043, 1.f, 1.f, ob, Gb, Pgb, pmb, po,
      owA,owB,gwA,gwB,pmA,pmB,pgA,pgB, stA,stB, lane, outl);
  scan_step<2,3,4,5,6, 4, 1, false>(2044, 1.f, 1.f, ob, Gb, Pgb, pmb, po,
      owA,owB,gwA,gwB,pmA,pmB,pgA,pgB, stA,stB, lane, outl);
  scan_step<3,4,5,6,7, 5, 2, false>(2045, 1.f, 1.f, ob, Gb, Pgb, pmb, po,
      owA,owB,gwA,gwB,pmA,pmB,pgA,pgB, stA,stB, lane, outl);
  scan_step<4,5,6,7,0, 6, 3, false>(2046, 1.f, 0.f, ob, Gb, Pgb, pmb, po,
      owA,owB,gwA,gwB,pmA,pmB,pgA,pgB, stA,stB, lane, outl);
  scan_step<5,6,7,0,1, 7, 4, true >(2047, 0.f, 0.f, ob, Gb, Pgb, pmb, po,
      owA,owB,gwA,gwB,pmA,pmB,pgA,pgB, stA,stB, lane, outl);
}

// ---------------------------------------------------------------------------
// Precompute GEMMs (unchanged): f32, 128x128x16 tiles, 8x8 microtile.
// mode 0: windowed-A GEMM (K=2560), n<512 -> PRE_mlp(+b_mlp) into Pm,
//         n>=512 -> PRE_gate(+b_gate). mode 1: G = O @ W_gate[:,2560:].T.
// ---------------------------------------------------------------------------
__global__ __launch_bounds__(256) void gemm_pre(
    const float* __restrict__ O, const float* __restrict__ Wm,
    const float* __restrict__ Wg, const float* __restrict__ bm,
    const float* __restrict__ bg, float* __restrict__ Pm,
    float* __restrict__ Pg, float* __restrict__ Gm, int mode) {
  const int BM = 128, BN = 128, BK = 16;
  __shared__ float As[BK][132];
  __shared__ float Bs[BK][132];

  int tidx = threadIdx.x;
  int bt0 = blockIdx.x * BM;
  int b = bt0 / Tq;
  int t0 = bt0 % Tq;
  int n0 = blockIdx.y * BN;
  int K = mode ? Dq : 5 * Dq;

  int tx = tidx % 16;
  int ty = tidx / 16;
  int lr = tidx >> 2;
  int lc = (tidx & 3) * 4;

  float acc[8][8];
#pragma unroll
  for (int i = 0; i < 8; i++)
#pragma unroll
    for (int j = 0; j < 8; j++) acc[i][j] = 0.f;

  for (int kb = 0; kb < K; kb += BK) {
#pragma unroll
    for (int h = 0; h < 2; h++) {
      int m = lr + h * 64;
      int t = t0 + m;
      float4 av;
      if (mode == 0) {
        int j = kb >> 9;
        int kcol = (kb & 511) + lc;
        int sh = 2 - t; if (sh < 0) sh = 0;
        int r = t - 2 + j + sh;
        int hi = t + 2; if (hi > Tq - 1) hi = Tq - 1;
        int lo = t - 2; if (lo < 0) lo = 0;
        int nv = hi - lo + 1;
        if (j < nv) {
          av = *reinterpret_cast<const float4*>(O + ((size_t)b * Tq + r) * Dq + kcol);
        } else {
          av = make_float4(0.f, 0.f, 0.f, 0.f);
        }
      } else {
        av = *reinterpret_cast<const float4*>(O + ((size_t)b * Tq + t) * Dq + kb + lc);
      }
      As[lc + 0][m] = av.x; As[lc + 1][m] = av.y;
      As[lc + 2][m] = av.z; As[lc + 3][m] = av.w;
    }
#pragma unroll
    for (int h = 0; h < 2; h++) {
      int n = lr + h * 64;
      int gn = n0 + n;
      const float* wrow;
      int col;
      if (mode == 0) {
        if (gn < 512) { wrow = Wm + (size_t)gn * 2560; col = kb + lc; }
        else          { wrow = Wg + (size_t)(gn - 512) * 3072; col = kb + lc; }
      } else {
        wrow = Wg + (size_t)gn * 3072; col = 2560 + kb + lc;
      }
      float4 bv = *reinterpret_cast<const float4*>(wrow + col);
      Bs[lc + 0][n] = bv.x; Bs[lc + 1][n] = bv.y;
      Bs[lc + 2][n] = bv.z; Bs[lc + 3][n] = bv.w;
    }
    __syncthreads();
#pragma unroll
    for (int kk = 0; kk < BK; kk++) {
      float a[8], bb[8];
      float4 a0 = *reinterpret_cast<float4*>(&As[kk][ty * 8]);
      float4 a1 = *reinterpret_cast<float4*>(&As[kk][ty * 8 + 4]);
      float4 b0 = *reinterpret_cast<float4*>(&Bs[kk][tx * 8]);
      float4 b1 = *reinterpret_cast<float4*>(&Bs[kk][tx * 8 + 4]);
      a[0]=a0.x; a[1]=a0.y; a[2]=a0.z; a[3]=a0.w; a[4]=a1.x; a[5]=a1.y; a[6]=a1.z; a[7]=a1.w;
      bb[0]=b0.x; bb[1]=b0.y; bb[2]=b0.z; bb[3]=b0.w; bb[4]=b1.x; bb[5]=b1.y; bb[6]=b1.z; bb[7]=b1.w;
#pragma unroll
      for (int i = 0; i < 8; i++)
#pragma unroll
        for (int j = 0; j < 8; j++) acc[i][j] = fmaf(a[i], bb[j], acc[i][j]);
    }
    __syncthreads();
  }

  int gn = n0 + tx * 8;
  float bias[8];
  float* dstbase;
  int coloff;
  if (mode == 0) {
    if (gn < 512) {
#pragma unroll
      for (int j = 0; j < 8; j++) bias[j] = bm[gn + j];
      dstbase = Pm; coloff = gn;
    } else {
#pragma unroll
      for (int j = 0; j < 8; j++) bias[j] = bg[gn - 512 + j];
      dstbase = Pg; coloff = gn - 512;
    }
  } else {
#pragma unroll
    for (int j = 0; j < 8; j++) bias[j] = 0.f;
    dstbase = Gm; coloff = gn;
  }
#pragma unroll
  for (int i = 0; i < 8; i++) {
    int bt = bt0 + ty * 8 + i;
    float4 v0 = make_float4(acc[i][0] + bias[0], acc[i][1] + bias[1],
                            acc[i][2] + bias[2], acc[i][3] + bias[3]);
    float4 v1 = make_float4(acc[i][4] + bias[4], acc[i][5] + bias[5],
                            acc[i][6] + bias[6], acc[i][7] + bias[7]);
    float4* d = reinterpret_cast<float4*>(dstbase + (size_t)bt * Dq + coloff);
    d[0] = v0;
    d[1] = v1;
  }
}

extern "C" void kernel_launch(void* const* d_in, const int* in_sizes, int n_in,
                              void* d_out, int out_size, void* d_ws, size_t ws_size,
                              hipStream_t stream) {
  const float* O  = (const float*)d_in[0];  // outputs [8,2048,512]
  const float* Wm = (const float*)d_in[1];  // W_mlp [512,2560]
  const float* bm = (const float*)d_in[2];  // b_mlp [512]
  const float* Wg = (const float*)d_in[3];  // W_gate [512,3072]
  const float* bg = (const float*)d_in[4];  // b_gate [512]
  float* out = (float*)d_out;               // [8,2048,512]

  const size_t NTOT = (size_t)Bq * Tq * Dq;  // 8.39M elements
  float* Pg = (float*)d_ws;                  // PRE_gate [8,2048,512]
  float* Gm = Pg + NTOT;                     // G        [8,2048,512]
  bool sep = ws_size >= (size_t)3 * NTOT * sizeof(float);
  float* Pm = sep ? (Gm + NTOT) : out;       // PRE_mlp (sep buffer if ws allows)

  gemm_pre<<<dim3(128, 8), dim3(256), 0, stream>>>(O, Wm, Wg, bm, bg, Pm, Pg, Gm, 0);
  gemm_pre<<<dim3(128, 4), dim3(256), 0, stream>>>(O, Wm, Wg, bm, bg, Pm, Pg, Gm, 1);

  scan_kernel<<<dim3(Bq), dim3(64), 0, stream>>>(O, Gm, Pg, Pm, out);
}